// Round 1
// baseline (1736.673 us; speedup 1.0000x reference)
//
#include <hip/hip_runtime.h>
#include <hip/hip_bf16.h>

// GAT: 3 layers. N=50000 nodes, E=800000 edges, H=4 heads.
// L0: 128 -> 4x64, elu ; L1: 256 -> 4x64, elu ; L2: 256 -> 4x256, mean over heads.
// Strategy: CSR-by-dst built per launch (no atomics in hot aggregation),
// fp32 tiled GEMM for projections, block-per-dst-node softmax-aggregate.

#define NN 50000
#define NE 800000
#define NH_HEADS 4

// ---------------- CSR build ----------------

__global__ void hist_kernel(const int* __restrict__ dst, int* __restrict__ deg, int E) {
    int e = blockIdx.x * 256 + threadIdx.x;
    if (e < E) atomicAdd(&deg[dst[e]], 1);
}

__global__ void scan_block_kernel(const int* __restrict__ deg, int* __restrict__ offs,
                                  int* __restrict__ bsums, int n) {
    __shared__ int s[256];
    int tid = threadIdx.x;
    int i = blockIdx.x * 256 + tid;
    int v = (i < n) ? deg[i] : 0;
    s[tid] = v;
    __syncthreads();
    for (int off = 1; off < 256; off <<= 1) {
        int x = (tid >= off) ? s[tid - off] : 0;
        __syncthreads();
        s[tid] += x;
        __syncthreads();
    }
    if (i < n) offs[i] = s[tid] - v;       // exclusive within block
    if (tid == 255) bsums[blockIdx.x] = s[255];
}

__global__ void scan_sums_kernel(const int* __restrict__ bsums, int* __restrict__ boffs, int nb) {
    __shared__ int s[256];
    int tid = threadIdx.x;
    int v = (tid < nb) ? bsums[tid] : 0;
    s[tid] = v;
    __syncthreads();
    for (int off = 1; off < 256; off <<= 1) {
        int x = (tid >= off) ? s[tid - off] : 0;
        __syncthreads();
        s[tid] += x;
        __syncthreads();
    }
    boffs[tid] = s[tid] - v;               // exclusive
}

__global__ void add_offs_kernel(int* __restrict__ offs, const int* __restrict__ boffs,
                                int* __restrict__ cursor, int n, int total) {
    int i = blockIdx.x * 256 + threadIdx.x;
    if (i < n) {
        int o = offs[i] + boffs[blockIdx.x];
        offs[i] = o;
        cursor[i] = o;
    }
    if (i == 0) offs[n] = total;
}

__global__ void scatter_kernel(const int* __restrict__ src, const int* __restrict__ dst,
                               int* __restrict__ cursor, int* __restrict__ psrc, int E) {
    int e = blockIdx.x * 256 + threadIdx.x;
    if (e < E) {
        int p = atomicAdd(&cursor[dst[e]], 1);
        psrc[p] = src[e];
    }
}

// ---------------- fp32 tiled GEMM: C[M,N] = A[M,K] @ B[K,N] ----------------
// BM=BN=64, BK=16, 256 threads, 4x4 per thread. N % 64 == 0, K % 16 == 0.

__global__ __launch_bounds__(256) void gemm_kernel(const float* __restrict__ A,
                                                   const float* __restrict__ B,
                                                   float* __restrict__ C,
                                                   int M, int N, int K) {
    __shared__ float As[16][65];
    __shared__ float Bs[16][65];
    int t = threadIdx.x;
    int bm = blockIdx.y * 64;
    int bn = blockIdx.x * 64;
    int tr = t >> 4, tc = t & 15;
    float acc[4][4] = {{0.f}};
    for (int k0 = 0; k0 < K; k0 += 16) {
#pragma unroll
        for (int i = 0; i < 4; i++) {
            int idx = i * 256 + t;
            int m = idx >> 4, kk = idx & 15;
            int gm = bm + m;
            As[kk][m] = (gm < M) ? A[(size_t)gm * K + (k0 + kk)] : 0.f;
            int kb = idx >> 6, nn = idx & 63;
            Bs[kb][nn] = B[(size_t)(k0 + kb) * N + (bn + nn)];
        }
        __syncthreads();
#pragma unroll
        for (int kk = 0; kk < 16; ++kk) {
            float a[4], b[4];
#pragma unroll
            for (int i = 0; i < 4; i++) a[i] = As[kk][tr * 4 + i];
#pragma unroll
            for (int j = 0; j < 4; j++) b[j] = Bs[kk][tc * 4 + j];
#pragma unroll
            for (int i = 0; i < 4; i++)
#pragma unroll
                for (int j = 0; j < 4; j++) acc[i][j] += a[i] * b[j];
        }
        __syncthreads();
    }
#pragma unroll
    for (int i = 0; i < 4; i++) {
        int gm = bm + tr * 4 + i;
        if (gm < M) {
#pragma unroll
            for (int j = 0; j < 4; j++)
                C[(size_t)gm * N + bn + tc * 4 + j] = acc[i][j];
        }
    }
}

// ---------------- attention score parts: el/er [N,H] ----------------
// one wave per (n,h); F = 64 or 256

__global__ __launch_bounds__(256) void elr_kernel(const float* __restrict__ z,
                                                  const float* __restrict__ al,
                                                  const float* __restrict__ ar,
                                                  float* __restrict__ el,
                                                  float* __restrict__ er,
                                                  int NH, int F) {
    int gid = blockIdx.x * 256 + threadIdx.x;
    int w = gid >> 6;
    int lane = threadIdx.x & 63;
    if (w >= NH) return;
    int n = w >> 2, h = w & 3;
    const float* zr = z + (size_t)n * (4 * F) + h * F;
    const float* alr = al + h * F;
    const float* arr = ar + h * F;
    float se = 0.f, sr = 0.f;
    for (int f = lane; f < F; f += 64) {
        float zv = zr[f];
        se += zv * alr[f];
        sr += zv * arr[f];
    }
#pragma unroll
    for (int off = 32; off > 0; off >>= 1) {
        se += __shfl_down(se, off);
        sr += __shfl_down(sr, off);
    }
    if (lane == 0) { el[w] = se; er[w] = sr; }
}

// ---------------- aggregation, layers 0/1 (H*F = 256), elu epilogue ----------------
// one block per dst node; thread t owns (h=t>>6, f=t&63)

__global__ __launch_bounds__(256) void agg_kernel(const float* __restrict__ z,
                                                  const float* __restrict__ el,
                                                  const float* __restrict__ er,
                                                  const int* __restrict__ offs,
                                                  const int* __restrict__ psrc,
                                                  const float* __restrict__ bias,
                                                  float* __restrict__ out) {
    int n = blockIdx.x;
    int t = threadIdx.x;
    int h = t >> 6;
    __shared__ float p_lds[64][4];
    __shared__ int src_lds[64];
    __shared__ float den_lds[4];
    if (t < 4) den_lds[t] = 0.f;
    int beg = offs[n], end = offs[n + 1];
    float acc = 0.f;
    int e_local = t >> 2, hh = t & 3;
    float er_n = er[n * 4 + hh];
    for (int base = beg; base < end; base += 64) {
        int cnt = min(64, end - base);
        __syncthreads();
        if (e_local < cnt) {
            int s = psrc[base + e_local];
            if (hh == 0) src_lds[e_local] = s;
            float sc = el[s * 4 + hh] + er_n;
            sc = (sc > 0.f) ? sc : 0.2f * sc;
            float p = __expf(sc);
            p_lds[e_local][hh] = p;
            atomicAdd(&den_lds[hh], p);
        }
        __syncthreads();
        for (int e = 0; e < cnt; ++e) {
            acc += p_lds[e][h] * z[(size_t)src_lds[e] * 256 + t];
        }
    }
    __syncthreads();
    float o = acc / fmaxf(den_lds[h], 1e-9f) + bias[t];
    out[(size_t)n * 256 + t] = (o > 0.f) ? o : (__expf(o) - 1.f);
}

// ---------------- aggregation, layer 2 (H=4, F=256), mean over heads -> d_out ----------------
// one block per dst node; thread t owns class c=t, accumulates all 4 heads

__global__ __launch_bounds__(256) void agg2_kernel(const float* __restrict__ z,
                                                   const float* __restrict__ el,
                                                   const float* __restrict__ er,
                                                   const int* __restrict__ offs,
                                                   const int* __restrict__ psrc,
                                                   const float* __restrict__ bias,
                                                   float* __restrict__ out) {
    int n = blockIdx.x, t = threadIdx.x;
    __shared__ float p_lds[64][4];
    __shared__ int src_lds[64];
    __shared__ float den_lds[4];
    if (t < 4) den_lds[t] = 0.f;
    int beg = offs[n], end = offs[n + 1];
    float a0 = 0.f, a1 = 0.f, a2 = 0.f, a3 = 0.f;
    int e_local = t >> 2, hh = t & 3;
    float er_n = er[n * 4 + hh];
    for (int base = beg; base < end; base += 64) {
        int cnt = min(64, end - base);
        __syncthreads();
        if (e_local < cnt) {
            int s = psrc[base + e_local];
            if (hh == 0) src_lds[e_local] = s;
            float sc = el[s * 4 + hh] + er_n;
            sc = (sc > 0.f) ? sc : 0.2f * sc;
            float p = __expf(sc);
            p_lds[e_local][hh] = p;
            atomicAdd(&den_lds[hh], p);
        }
        __syncthreads();
        for (int e = 0; e < cnt; ++e) {
            const float* zr = z + (size_t)src_lds[e] * 1024;
            float p0 = p_lds[e][0], p1 = p_lds[e][1], p2 = p_lds[e][2], p3 = p_lds[e][3];
            a0 += p0 * zr[t];
            a1 += p1 * zr[256 + t];
            a2 += p2 * zr[512 + t];
            a3 += p3 * zr[768 + t];
        }
    }
    __syncthreads();
    float o = a0 / fmaxf(den_lds[0], 1e-9f) + bias[t]
            + a1 / fmaxf(den_lds[1], 1e-9f) + bias[256 + t]
            + a2 / fmaxf(den_lds[2], 1e-9f) + bias[512 + t]
            + a3 / fmaxf(den_lds[3], 1e-9f) + bias[768 + t];
    out[(size_t)n * 256 + t] = o * 0.25f;
}

// ---------------- launch ----------------

extern "C" void kernel_launch(void* const* d_in, const int* in_sizes, int n_in,
                              void* d_out, int out_size, void* d_ws, size_t ws_size,
                              hipStream_t stream) {
    const float* feat = (const float*)d_in[0];
    const float* W0 = (const float*)d_in[1];
    const float* al0 = (const float*)d_in[2];
    const float* ar0 = (const float*)d_in[3];
    const float* b0 = (const float*)d_in[4];
    const float* W1 = (const float*)d_in[5];
    const float* al1 = (const float*)d_in[6];
    const float* ar1 = (const float*)d_in[7];
    const float* b1 = (const float*)d_in[8];
    const float* W2 = (const float*)d_in[9];
    const float* al2 = (const float*)d_in[10];
    const float* ar2 = (const float*)d_in[11];
    const float* b2 = (const float*)d_in[12];
    const int* src = (const int*)d_in[13];
    const int* dst = (const int*)d_in[14];
    float* out = (float*)d_out;

    // workspace layout (~261.4 MB)
    float* z = (float*)d_ws;                       // 50000*1024
    float* hbuf = z + (size_t)NN * 1024;           // 50000*256
    float* el = hbuf + (size_t)NN * 256;           // 200000
    float* er = el + (size_t)NN * NH_HEADS;        // 200000
    int* deg = (int*)(er + (size_t)NN * NH_HEADS); // 50000
    int* offs = deg + NN;                          // 50001 (+1 pad)
    int* cursor = offs + NN + 2;                   // 50000
    int* bsums = cursor + NN;                      // 256
    int* boffs = bsums + 256;                      // 256
    int* psrc = boffs + 256;                       // 800000

    // ---- CSR build (by dst) ----
    hipMemsetAsync(deg, 0, NN * sizeof(int), stream);
    hist_kernel<<<(NE + 255) / 256, 256, 0, stream>>>(dst, deg, NE);
    int nb = (NN + 255) / 256; // 196
    scan_block_kernel<<<nb, 256, 0, stream>>>(deg, offs, bsums, NN);
    scan_sums_kernel<<<1, 256, 0, stream>>>(bsums, boffs, nb);
    add_offs_kernel<<<nb, 256, 0, stream>>>(offs, boffs, cursor, NN, NE);
    scatter_kernel<<<(NE + 255) / 256, 256, 0, stream>>>(src, dst, cursor, psrc, NE);

    int mblocks = (NN + 63) / 64; // 782

    // ---- layer 0: 128 -> 4x64, elu ----
    gemm_kernel<<<dim3(256 / 64, mblocks), 256, 0, stream>>>(feat, W0, z, NN, 256, 128);
    elr_kernel<<<(NN * NH_HEADS) / 4, 256, 0, stream>>>(z, al0, ar0, el, er, NN * NH_HEADS, 64);
    agg_kernel<<<NN, 256, 0, stream>>>(z, el, er, offs, psrc, b0, hbuf);

    // ---- layer 1: 256 -> 4x64, elu ----
    gemm_kernel<<<dim3(256 / 64, mblocks), 256, 0, stream>>>(hbuf, W1, z, NN, 256, 256);
    elr_kernel<<<(NN * NH_HEADS) / 4, 256, 0, stream>>>(z, al1, ar1, el, er, NN * NH_HEADS, 64);
    agg_kernel<<<NN, 256, 0, stream>>>(z, el, er, offs, psrc, b1, hbuf);

    // ---- layer 2: 256 -> 4x256, mean over heads ----
    gemm_kernel<<<dim3(1024 / 64, mblocks), 256, 0, stream>>>(hbuf, W2, z, NN, 1024, 256);
    elr_kernel<<<(NN * NH_HEADS) / 4, 256, 0, stream>>>(z, al2, ar2, el, er, NN * NH_HEADS, 256);
    agg2_kernel<<<NN, 256, 0, stream>>>(z, el, er, offs, psrc, b2, out);
}

// Round 3
// 1267.437 us; speedup vs baseline: 1.3702x; 1.3702x over previous
//
#include <hip/hip_runtime.h>
#include <hip/hip_bf16.h>

// GAT: 3 layers. N=50000 nodes, E=800000 edges, H=4 heads.
// R3: MFMA GEMM via bf16 hi/lo split. A converted in-kernel during LDS
// staging (fragment-order, conflict-free); B pre-formatted hi/lo in global
// (<=1MB, L2-resident). Workspace = R1 layout + 1MB (fits).

#define NN 50000
#define NE 800000
#define NH_HEADS 4

typedef __attribute__((ext_vector_type(8))) short short8;
typedef __attribute__((ext_vector_type(4))) float floatx4;

__device__ inline short f2bf_rne(float x) {
    union { float f; unsigned u; } v; v.f = x;
    unsigned r = v.u + 0x7fff + ((v.u >> 16) & 1);
    return (short)(r >> 16);
}
__device__ inline float bf2f(short s) {
    union { unsigned u; float f; } v; v.u = ((unsigned)(unsigned short)s) << 16;
    return v.f;
}

// split 8 consecutive fp32 into bf16 hi (trunc) + lo (trunc of residual)
__device__ inline void cvt8(const float* __restrict__ p, short8& h, short8& l) {
    float4 x0 = ((const float4*)p)[0];
    float4 x1 = ((const float4*)p)[1];
    float xs[8] = {x0.x, x0.y, x0.z, x0.w, x1.x, x1.y, x1.z, x1.w};
#pragma unroll
    for (int j = 0; j < 8; ++j) {
        union { float f; unsigned u; } v; v.f = xs[j];
        short hh = (short)(v.u >> 16);
        h[j] = hh;
        float r = v.f - bf2f(hh);
        union { float f; unsigned u; } rv; rv.f = r;
        l[j] = (short)(rv.u >> 16);
    }
}

// ---------------- CSR build ----------------

__global__ void hist_kernel(const int* __restrict__ dst, int* __restrict__ deg, int E) {
    int e = blockIdx.x * 256 + threadIdx.x;
    if (e < E) atomicAdd(&deg[dst[e]], 1);
}

__global__ void scan_block_kernel(const int* __restrict__ deg, int* __restrict__ offs,
                                  int* __restrict__ bsums, int n) {
    __shared__ int s[256];
    int tid = threadIdx.x;
    int i = blockIdx.x * 256 + tid;
    int v = (i < n) ? deg[i] : 0;
    s[tid] = v;
    __syncthreads();
    for (int off = 1; off < 256; off <<= 1) {
        int x = (tid >= off) ? s[tid - off] : 0;
        __syncthreads();
        s[tid] += x;
        __syncthreads();
    }
    if (i < n) offs[i] = s[tid] - v;
    if (tid == 255) bsums[blockIdx.x] = s[255];
}

__global__ void scan_sums_kernel(const int* __restrict__ bsums, int* __restrict__ boffs, int nb) {
    __shared__ int s[256];
    int tid = threadIdx.x;
    int v = (tid < nb) ? bsums[tid] : 0;
    s[tid] = v;
    __syncthreads();
    for (int off = 1; off < 256; off <<= 1) {
        int x = (tid >= off) ? s[tid - off] : 0;
        __syncthreads();
        s[tid] += x;
        __syncthreads();
    }
    boffs[tid] = s[tid] - v;
}

__global__ void add_offs_kernel(int* __restrict__ offs, const int* __restrict__ boffs,
                                int* __restrict__ cursor, int n, int total) {
    int i = blockIdx.x * 256 + threadIdx.x;
    if (i < n) {
        int o = offs[i] + boffs[blockIdx.x];
        offs[i] = o;
        cursor[i] = o;
    }
    if (i == 0) offs[n] = total;
}

__global__ void scatter_kernel(const int* __restrict__ src, const int* __restrict__ dst,
                               int* __restrict__ cursor, int* __restrict__ psrc, int E) {
    int e = blockIdx.x * 256 + threadIdx.x;
    if (e < E) {
        int p = atomicAdd(&cursor[dst[e]], 1);
        psrc[p] = src[e];
    }
}

// ---------------- B -> bf16 hi/lo in MFMA B-fragment order ----------------
// B [K,N]: chunk c (32 k) x col-group g (16 n):
//   lane = (n&15) + 16*((k&31)>>3), j = k&7 ; offset (short8) = (c*(N/16)+g)*64 + lane

__global__ __launch_bounds__(256) void splitB_kernel(const float* __restrict__ B,
                                                     short* __restrict__ hi,
                                                     short* __restrict__ lo,
                                                     int K, int N) {
    int tid = blockIdx.x * 256 + threadIdx.x;
    int NG = N >> 4;
    int total = (K >> 5) * NG * 64;
    if (tid >= total) return;
    int lane = tid & 63;
    int rc = tid >> 6;
    int g = rc % NG, c = rc / NG;
    int n = g * 16 + (lane & 15);
    int k = c * 32 + (lane >> 4) * 8;
    short8 hv, lv;
#pragma unroll
    for (int j = 0; j < 8; ++j) {
        float x = B[(size_t)(k + j) * N + n];
        short h = f2bf_rne(x);
        hv[j] = h;
        lv[j] = f2bf_rne(x - bf2f(h));
    }
    ((short8*)hi)[tid] = hv;
    ((short8*)lo)[tid] = lv;
}

// ---------------- MFMA GEMM: C[M,N] = A@B, A fp32 split in-kernel ----------------
// block = 256 (4 waves), tile 128(M) x 64(N), BK=32.
// wave w: rows [bm+32w, bm+32w+32), all 64 cols. 24 mfma / wave / chunk.

__device__ inline floatx4 mfma16(short8 a, short8 b, floatx4 c) {
    return __builtin_amdgcn_mfma_f32_16x16x32_bf16(a, b, c, 0, 0, 0);
}

__global__ __launch_bounds__(256) void gemm_mfma(const float* __restrict__ A,
                                                 const short* __restrict__ Bh,
                                                 const short* __restrict__ Bl,
                                                 float* __restrict__ C,
                                                 int M, int N, int K) {
    int KC = K >> 5;
    int NG = N >> 4;
    __shared__ short8 AhL[512];   // [m-tile(8)][lane(64)]
    __shared__ short8 AlL[512];
    int t = threadIdx.x;
    int lane = t & 63;
    int w = t >> 6;
    int bm = blockIdx.y * 128;
    int bn = blockIdx.x * 64;
    int g0 = bn >> 4;
    const short8* pBh = (const short8*)Bh;
    const short8* pBl = (const short8*)Bl;

    floatx4 acc[2][4] = {};

    // this thread stages octets o1=t, o2=t+256 of the 128x32 A-tile:
    // octet o: m = (o>>6)*16 + (o&15), k-octet = (o>>4)&3
    int m1 = ((t >> 6) << 4) + (t & 15);
    int ko1 = (t >> 4) & 3;
    int o2 = t + 256;
    int m2 = ((o2 >> 6) << 4) + (o2 & 15);
    int ko2 = (o2 >> 4) & 3;
    bool v1 = (bm + m1) < M;
    bool v2 = (bm + m2) < M;
    const float* A1 = A + (size_t)(bm + m1) * K + ko1 * 8;
    const float* A2 = A + (size_t)(bm + m2) * K + ko2 * 8;

    for (int c = 0; c < KC; ++c) {
        short8 h1, l1, h2, l2;
        if (v1) cvt8(A1 + c * 32, h1, l1);
        else {
#pragma unroll
            for (int j = 0; j < 8; ++j) { h1[j] = 0; l1[j] = 0; }
        }
        if (v2) cvt8(A2 + c * 32, h2, l2);
        else {
#pragma unroll
            for (int j = 0; j < 8; ++j) { h2[j] = 0; l2[j] = 0; }
        }
        __syncthreads();           // prev iter's LDS reads done
        AhL[t] = h1; AlL[t] = l1;
        AhL[o2] = h2; AlL[o2] = l2;
        __syncthreads();

        short8 ah[2], al[2], bh[4], bl[4];
#pragma unroll
        for (int st = 0; st < 2; ++st) {
            ah[st] = AhL[(w * 2 + st) * 64 + lane];
            al[st] = AlL[(w * 2 + st) * 64 + lane];
        }
#pragma unroll
        for (int sn = 0; sn < 4; ++sn) {
            bh[sn] = pBh[((size_t)c * NG + g0 + sn) * 64 + lane];
            bl[sn] = pBl[((size_t)c * NG + g0 + sn) * 64 + lane];
        }
#pragma unroll
        for (int st = 0; st < 2; ++st)
#pragma unroll
            for (int sn = 0; sn < 4; ++sn) {
                acc[st][sn] = mfma16(ah[st], bh[sn], acc[st][sn]);
                acc[st][sn] = mfma16(al[st], bh[sn], acc[st][sn]);
                acc[st][sn] = mfma16(ah[st], bl[sn], acc[st][sn]);
            }
    }

    // C/D layout: col = lane&15, row = (lane>>4)*4 + reg
    int row0 = bm + w * 32 + (lane >> 4) * 4;
    int col0 = bn + (lane & 15);
#pragma unroll
    for (int st = 0; st < 2; ++st)
#pragma unroll
        for (int r = 0; r < 4; ++r) {
            int row = row0 + st * 16 + r;
            if (row < M) {
#pragma unroll
                for (int sn = 0; sn < 4; ++sn)
                    C[(size_t)row * N + col0 + sn * 16] = acc[st][sn][r];
            }
        }
}

// ---------------- attention score parts: el/er [N,H] ----------------

__global__ __launch_bounds__(256) void elr_kernel(const float* __restrict__ z,
                                                  const float* __restrict__ al,
                                                  const float* __restrict__ ar,
                                                  float* __restrict__ el,
                                                  float* __restrict__ er,
                                                  int NH, int F) {
    int gid = blockIdx.x * 256 + threadIdx.x;
    int w = gid >> 6;
    int lane = threadIdx.x & 63;
    if (w >= NH) return;
    int n = w >> 2, h = w & 3;
    const float* zr = z + (size_t)n * (4 * F) + h * F;
    const float* alr = al + h * F;
    const float* arr = ar + h * F;
    float se = 0.f, sr = 0.f;
    for (int f = lane; f < F; f += 64) {
        float zv = zr[f];
        se += zv * alr[f];
        sr += zv * arr[f];
    }
#pragma unroll
    for (int off = 32; off > 0; off >>= 1) {
        se += __shfl_down(se, off);
        sr += __shfl_down(sr, off);
    }
    if (lane == 0) { el[w] = se; er[w] = sr; }
}

// ---------------- aggregation, layers 0/1 (H*F = 256), elu epilogue ----------------

__global__ __launch_bounds__(256) void agg_kernel(const float* __restrict__ z,
                                                  const float* __restrict__ el,
                                                  const float* __restrict__ er,
                                                  const int* __restrict__ offs,
                                                  const int* __restrict__ psrc,
                                                  const float* __restrict__ bias,
                                                  float* __restrict__ out) {
    int n = blockIdx.x;
    int t = threadIdx.x;
    int h = t >> 6;
    __shared__ float p_lds[64][4];
    __shared__ int src_lds[64];
    __shared__ float den_lds[4];
    if (t < 4) den_lds[t] = 0.f;
    int beg = offs[n], end = offs[n + 1];
    float acc = 0.f;
    int e_local = t >> 2, hh = t & 3;
    float er_n = er[n * 4 + hh];
    for (int base = beg; base < end; base += 64) {
        int cnt = min(64, end - base);
        __syncthreads();
        if (e_local < cnt) {
            int s = psrc[base + e_local];
            if (hh == 0) src_lds[e_local] = s;
            float sc = el[s * 4 + hh] + er_n;
            sc = (sc > 0.f) ? sc : 0.2f * sc;
            float p = __expf(sc);
            p_lds[e_local][hh] = p;
            atomicAdd(&den_lds[hh], p);
        }
        __syncthreads();
        for (int e = 0; e < cnt; ++e) {
            acc += p_lds[e][h] * z[(size_t)src_lds[e] * 256 + t];
        }
    }
    __syncthreads();
    float o = acc / fmaxf(den_lds[h], 1e-9f) + bias[t];
    out[(size_t)n * 256 + t] = (o > 0.f) ? o : (__expf(o) - 1.f);
}

// ---------------- aggregation, layer 2 (H=4, F=256), mean over heads ----------------

__global__ __launch_bounds__(256) void agg2_kernel(const float* __restrict__ z,
                                                   const float* __restrict__ el,
                                                   const float* __restrict__ er,
                                                   const int* __restrict__ offs,
                                                   const int* __restrict__ psrc,
                                                   const float* __restrict__ bias,
                                                   float* __restrict__ out) {
    int n = blockIdx.x, t = threadIdx.x;
    __shared__ float p_lds[64][4];
    __shared__ int src_lds[64];
    __shared__ float den_lds[4];
    if (t < 4) den_lds[t] = 0.f;
    int beg = offs[n], end = offs[n + 1];
    float a0 = 0.f, a1 = 0.f, a2 = 0.f, a3 = 0.f;
    int e_local = t >> 2, hh = t & 3;
    float er_n = er[n * 4 + hh];
    for (int base = beg; base < end; base += 64) {
        int cnt = min(64, end - base);
        __syncthreads();
        if (e_local < cnt) {
            int s = psrc[base + e_local];
            if (hh == 0) src_lds[e_local] = s;
            float sc = el[s * 4 + hh] + er_n;
            sc = (sc > 0.f) ? sc : 0.2f * sc;
            float p = __expf(sc);
            p_lds[e_local][hh] = p;
            atomicAdd(&den_lds[hh], p);
        }
        __syncthreads();
        for (int e = 0; e < cnt; ++e) {
            const float* zr = z + (size_t)src_lds[e] * 1024;
            float p0 = p_lds[e][0], p1 = p_lds[e][1], p2 = p_lds[e][2], p3 = p_lds[e][3];
            a0 += p0 * zr[t];
            a1 += p1 * zr[256 + t];
            a2 += p2 * zr[512 + t];
            a3 += p3 * zr[768 + t];
        }
    }
    __syncthreads();
    float o = a0 / fmaxf(den_lds[0], 1e-9f) + bias[t]
            + a1 / fmaxf(den_lds[1], 1e-9f) + bias[256 + t]
            + a2 / fmaxf(den_lds[2], 1e-9f) + bias[512 + t]
            + a3 / fmaxf(den_lds[3], 1e-9f) + bias[768 + t];
    out[(size_t)n * 256 + t] = o * 0.25f;
}

// ---------------- launch ----------------

extern "C" void kernel_launch(void* const* d_in, const int* in_sizes, int n_in,
                              void* d_out, int out_size, void* d_ws, size_t ws_size,
                              hipStream_t stream) {
    const float* feat = (const float*)d_in[0];
    const float* W0 = (const float*)d_in[1];
    const float* al0 = (const float*)d_in[2];
    const float* ar0 = (const float*)d_in[3];
    const float* b0 = (const float*)d_in[4];
    const float* W1 = (const float*)d_in[5];
    const float* al1 = (const float*)d_in[6];
    const float* ar1 = (const float*)d_in[7];
    const float* b1 = (const float*)d_in[8];
    const float* W2 = (const float*)d_in[9];
    const float* al2 = (const float*)d_in[10];
    const float* ar2 = (const float*)d_in[11];
    const float* b2 = (const float*)d_in[12];
    const int* src = (const int*)d_in[13];
    const int* dst = (const int*)d_in[14];
    float* out = (float*)d_out;

    // workspace layout (~262.5 MB)
    float* z = (float*)d_ws;                       // 50000*1024
    float* hbuf = z + (size_t)NN * 1024;           // 50000*256
    float* el = hbuf + (size_t)NN * 256;           // 200000
    float* er = el + (size_t)NN * NH_HEADS;        // 200000
    int* deg = (int*)(er + (size_t)NN * NH_HEADS); // 50000
    int* offs = deg + NN;                          // 50001 (+1 pad)
    int* cursor = offs + NN + 2;                   // 50000
    int* bsums = cursor + NN;                      // 256
    int* boffs = bsums + 256;                      // 256
    int* psrc = boffs + 256;                       // 800000 (+2 pad)
    short* Bh = (short*)(psrc + NE + 2);           // 262144 shorts (max K*N)
    short* Bl = Bh + 262144;                       // 262144 shorts

    // ---- CSR build (by dst) ----
    hipMemsetAsync(deg, 0, NN * sizeof(int), stream);
    hist_kernel<<<(NE + 255) / 256, 256, 0, stream>>>(dst, deg, NE);
    int nb = (NN + 255) / 256; // 196
    scan_block_kernel<<<nb, 256, 0, stream>>>(deg, offs, bsums, NN);
    scan_sums_kernel<<<1, 256, 0, stream>>>(bsums, boffs, nb);
    add_offs_kernel<<<nb, 256, 0, stream>>>(offs, boffs, cursor, NN, NE);
    scatter_kernel<<<(NE + 255) / 256, 256, 0, stream>>>(src, dst, cursor, psrc, NE);

    int mb128 = (NN + 127) / 128; // 391

    // ---- layer 0: 128 -> 4x64, elu ----
    {
        int totB = (128 / 32) * (256 / 16) * 64;          // 4096
        splitB_kernel<<<(totB + 255) / 256, 256, 0, stream>>>(W0, Bh, Bl, 128, 256);
        gemm_mfma<<<dim3(256 / 64, mb128), 256, 0, stream>>>(feat, Bh, Bl, z, NN, 256, 128);
    }
    elr_kernel<<<(NN * NH_HEADS) / 4, 256, 0, stream>>>(z, al0, ar0, el, er, NN * NH_HEADS, 64);
    agg_kernel<<<NN, 256, 0, stream>>>(z, el, er, offs, psrc, b0, hbuf);

    // ---- layer 1: 256 -> 4x64, elu ----
    {
        int totB = (256 / 32) * (256 / 16) * 64;          // 8192
        splitB_kernel<<<(totB + 255) / 256, 256, 0, stream>>>(W1, Bh, Bl, 256, 256);
        gemm_mfma<<<dim3(256 / 64, mb128), 256, 0, stream>>>(hbuf, Bh, Bl, z, NN, 256, 256);
    }
    elr_kernel<<<(NN * NH_HEADS) / 4, 256, 0, stream>>>(z, al1, ar1, el, er, NN * NH_HEADS, 64);
    agg_kernel<<<NN, 256, 0, stream>>>(z, el, er, offs, psrc, b1, hbuf);

    // ---- layer 2: 256 -> 4x256, mean over heads ----
    {
        int totB = (256 / 32) * (1024 / 16) * 64;         // 32768
        splitB_kernel<<<(totB + 255) / 256, 256, 0, stream>>>(W2, Bh, Bl, 256, 1024);
        gemm_mfma<<<dim3(1024 / 64, mb128), 256, 0, stream>>>(hbuf, Bh, Bl, z, NN, 1024, 256);
    }
    elr_kernel<<<(NN * NH_HEADS) / 4, 256, 0, stream>>>(z, al2, ar2, el, er, NN * NH_HEADS, 256);
    agg2_kernel<<<NN, 256, 0, stream>>>(z, el, er, offs, psrc, b2, out);
}

// Round 4
// 995.130 us; speedup vs baseline: 1.7452x; 1.2736x over previous
//
#include <hip/hip_runtime.h>
#include <hip/hip_bf16.h>

// GAT: 3 layers. N=50000 nodes, E=800000 edges, H=4 heads.
// R4: layer 2 restructured — aggregate h1 first (1KB/edge, L3-resident),
// then project with MFMA GEMM vs permuted W2. z2 never materialized.
// el2/er2 computed from h1 via precomputed W2_h@al2 / W2_h@ar2.

#define NN 50000
#define NE 800000
#define NH_HEADS 4

typedef __attribute__((ext_vector_type(8))) short short8;
typedef __attribute__((ext_vector_type(4))) float floatx4;

__device__ inline short f2bf_rne(float x) {
    union { float f; unsigned u; } v; v.f = x;
    unsigned r = v.u + 0x7fff + ((v.u >> 16) & 1);
    return (short)(r >> 16);
}
__device__ inline float bf2f(short s) {
    union { unsigned u; float f; } v; v.u = ((unsigned)(unsigned short)s) << 16;
    return v.f;
}

__device__ inline void cvt8(const float* __restrict__ p, short8& h, short8& l) {
    float4 x0 = ((const float4*)p)[0];
    float4 x1 = ((const float4*)p)[1];
    float xs[8] = {x0.x, x0.y, x0.z, x0.w, x1.x, x1.y, x1.z, x1.w};
#pragma unroll
    for (int j = 0; j < 8; ++j) {
        union { float f; unsigned u; } v; v.f = xs[j];
        short hh = (short)(v.u >> 16);
        h[j] = hh;
        float r = v.f - bf2f(hh);
        union { float f; unsigned u; } rv; rv.f = r;
        l[j] = (short)(rv.u >> 16);
    }
}

// ---------------- CSR build ----------------

__global__ void hist_kernel(const int* __restrict__ dst, int* __restrict__ deg, int E) {
    int e = blockIdx.x * 256 + threadIdx.x;
    if (e < E) atomicAdd(&deg[dst[e]], 1);
}

__global__ void scan_block_kernel(const int* __restrict__ deg, int* __restrict__ offs,
                                  int* __restrict__ bsums, int n) {
    __shared__ int s[256];
    int tid = threadIdx.x;
    int i = blockIdx.x * 256 + tid;
    int v = (i < n) ? deg[i] : 0;
    s[tid] = v;
    __syncthreads();
    for (int off = 1; off < 256; off <<= 1) {
        int x = (tid >= off) ? s[tid - off] : 0;
        __syncthreads();
        s[tid] += x;
        __syncthreads();
    }
    if (i < n) offs[i] = s[tid] - v;
    if (tid == 255) bsums[blockIdx.x] = s[255];
}

__global__ void scan_sums_kernel(const int* __restrict__ bsums, int* __restrict__ boffs, int nb) {
    __shared__ int s[256];
    int tid = threadIdx.x;
    int v = (tid < nb) ? bsums[tid] : 0;
    s[tid] = v;
    __syncthreads();
    for (int off = 1; off < 256; off <<= 1) {
        int x = (tid >= off) ? s[tid - off] : 0;
        __syncthreads();
        s[tid] += x;
        __syncthreads();
    }
    boffs[tid] = s[tid] - v;
}

__global__ void add_offs_kernel(int* __restrict__ offs, const int* __restrict__ boffs,
                                int* __restrict__ cursor, int n, int total) {
    int i = blockIdx.x * 256 + threadIdx.x;
    if (i < n) {
        int o = offs[i] + boffs[blockIdx.x];
        offs[i] = o;
        cursor[i] = o;
    }
    if (i == 0) offs[n] = total;
}

__global__ void scatter_kernel(const int* __restrict__ src, const int* __restrict__ dst,
                               int* __restrict__ cursor, int* __restrict__ psrc, int E) {
    int e = blockIdx.x * 256 + threadIdx.x;
    if (e < E) {
        int p = atomicAdd(&cursor[dst[e]], 1);
        psrc[p] = src[e];
    }
}

// ---------------- B -> bf16 hi/lo in MFMA B-fragment order ----------------

__global__ __launch_bounds__(256) void splitB_kernel(const float* __restrict__ B,
                                                     short* __restrict__ hi,
                                                     short* __restrict__ lo,
                                                     int K, int N) {
    int tid = blockIdx.x * 256 + threadIdx.x;
    int NG = N >> 4;
    int total = (K >> 5) * NG * 64;
    if (tid >= total) return;
    int lane = tid & 63;
    int rc = tid >> 6;
    int g = rc % NG, c = rc / NG;
    int n = g * 16 + (lane & 15);
    int k = c * 32 + (lane >> 4) * 8;
    short8 hv, lv;
#pragma unroll
    for (int j = 0; j < 8; ++j) {
        float x = B[(size_t)(k + j) * N + n];
        short h = f2bf_rne(x);
        hv[j] = h;
        lv[j] = f2bf_rne(x - bf2f(h));
    }
    ((short8*)hi)[tid] = hv;
    ((short8*)lo)[tid] = lv;
}

// permuted-W2 B for the final GEMM: Bp[h*256+k, c] = W2[k, h*256+c]; K=1024, N=256
__global__ __launch_bounds__(256) void splitB2_kernel(const float* __restrict__ W2,
                                                      short* __restrict__ hi,
                                                      short* __restrict__ lo) {
    int tid = blockIdx.x * 256 + threadIdx.x;
    const int NG = 16;
    int total = (1024 >> 5) * NG * 64;   // 32768
    if (tid >= total) return;
    int lane = tid & 63;
    int rc = tid >> 6;
    int g = rc % NG, c = rc / NG;
    int n = g * 16 + (lane & 15);
    int kk = c * 32 + (lane >> 4) * 8;
    short8 hv, lv;
#pragma unroll
    for (int j = 0; j < 8; ++j) {
        int kg = kk + j;
        int h = kg >> 8, k = kg & 255;
        float x = W2[(size_t)k * 1024 + h * 256 + n];
        short hb = f2bf_rne(x);
        hv[j] = hb;
        lv[j] = f2bf_rne(x - bf2f(hb));
    }
    ((short8*)hi)[tid] = hv;
    ((short8*)lo)[tid] = lv;
}

// ---------------- MFMA GEMM core ----------------

__device__ inline floatx4 mfma16(short8 a, short8 b, floatx4 c) {
    return __builtin_amdgcn_mfma_f32_16x16x32_bf16(a, b, c, 0, 0, 0);
}

__global__ __launch_bounds__(256) void gemm_mfma(const float* __restrict__ A,
                                                 const short* __restrict__ Bh,
                                                 const short* __restrict__ Bl,
                                                 float* __restrict__ C,
                                                 int M, int N, int K) {
    int KC = K >> 5;
    int NG = N >> 4;
    __shared__ short8 AhL[512];
    __shared__ short8 AlL[512];
    int t = threadIdx.x;
    int lane = t & 63;
    int w = t >> 6;
    int bm = blockIdx.y * 128;
    int bn = blockIdx.x * 64;
    int g0 = bn >> 4;
    const short8* pBh = (const short8*)Bh;
    const short8* pBl = (const short8*)Bl;

    floatx4 acc[2][4] = {};

    int m1 = ((t >> 6) << 4) + (t & 15);
    int ko1 = (t >> 4) & 3;
    int o2 = t + 256;
    int m2 = ((o2 >> 6) << 4) + (o2 & 15);
    int ko2 = (o2 >> 4) & 3;
    bool v1 = (bm + m1) < M;
    bool v2 = (bm + m2) < M;
    const float* A1 = A + (size_t)(bm + m1) * K + ko1 * 8;
    const float* A2 = A + (size_t)(bm + m2) * K + ko2 * 8;

    for (int c = 0; c < KC; ++c) {
        short8 h1v, l1v, h2v, l2v;
        if (v1) cvt8(A1 + c * 32, h1v, l1v);
        else {
#pragma unroll
            for (int j = 0; j < 8; ++j) { h1v[j] = 0; l1v[j] = 0; }
        }
        if (v2) cvt8(A2 + c * 32, h2v, l2v);
        else {
#pragma unroll
            for (int j = 0; j < 8; ++j) { h2v[j] = 0; l2v[j] = 0; }
        }
        __syncthreads();
        AhL[t] = h1v; AlL[t] = l1v;
        AhL[o2] = h2v; AlL[o2] = l2v;
        __syncthreads();

        short8 ah[2], al[2], bh[4], bl[4];
#pragma unroll
        for (int st = 0; st < 2; ++st) {
            ah[st] = AhL[(w * 2 + st) * 64 + lane];
            al[st] = AlL[(w * 2 + st) * 64 + lane];
        }
#pragma unroll
        for (int sn = 0; sn < 4; ++sn) {
            bh[sn] = pBh[((size_t)c * NG + g0 + sn) * 64 + lane];
            bl[sn] = pBl[((size_t)c * NG + g0 + sn) * 64 + lane];
        }
#pragma unroll
        for (int st = 0; st < 2; ++st)
#pragma unroll
            for (int sn = 0; sn < 4; ++sn) {
                acc[st][sn] = mfma16(ah[st], bh[sn], acc[st][sn]);
                acc[st][sn] = mfma16(al[st], bh[sn], acc[st][sn]);
                acc[st][sn] = mfma16(ah[st], bl[sn], acc[st][sn]);
            }
    }

    int row0 = bm + w * 32 + (lane >> 4) * 4;
    int col0 = bn + (lane & 15);
#pragma unroll
    for (int st = 0; st < 2; ++st)
#pragma unroll
        for (int r = 0; r < 4; ++r) {
            int row = row0 + st * 16 + r;
            if (row < M) {
#pragma unroll
                for (int sn = 0; sn < 4; ++sn)
                    C[(size_t)row * N + col0 + sn * 16] = acc[st][sn][r];
            }
        }
}

// final GEMM: out = 0.25*(aggH @ Bp) + 0.25*sum_h b2_h ; M=NN, N=256, K=1024
__global__ __launch_bounds__(256) void gemm_fin(const float* __restrict__ A,
                                                const short* __restrict__ Bh,
                                                const short* __restrict__ Bl,
                                                const float* __restrict__ b2,
                                                float* __restrict__ C,
                                                int M, int N, int K) {
    int KC = K >> 5;
    int NG = N >> 4;
    __shared__ short8 AhL[512];
    __shared__ short8 AlL[512];
    int t = threadIdx.x;
    int lane = t & 63;
    int w = t >> 6;
    int bm = blockIdx.y * 128;
    int bn = blockIdx.x * 64;
    int g0 = bn >> 4;
    const short8* pBh = (const short8*)Bh;
    const short8* pBl = (const short8*)Bl;

    floatx4 acc[2][4] = {};

    int m1 = ((t >> 6) << 4) + (t & 15);
    int ko1 = (t >> 4) & 3;
    int o2 = t + 256;
    int m2 = ((o2 >> 6) << 4) + (o2 & 15);
    int ko2 = (o2 >> 4) & 3;
    bool v1 = (bm + m1) < M;
    bool v2 = (bm + m2) < M;
    const float* A1 = A + (size_t)(bm + m1) * K + ko1 * 8;
    const float* A2 = A + (size_t)(bm + m2) * K + ko2 * 8;

    for (int c = 0; c < KC; ++c) {
        short8 h1v, l1v, h2v, l2v;
        if (v1) cvt8(A1 + c * 32, h1v, l1v);
        else {
#pragma unroll
            for (int j = 0; j < 8; ++j) { h1v[j] = 0; l1v[j] = 0; }
        }
        if (v2) cvt8(A2 + c * 32, h2v, l2v);
        else {
#pragma unroll
            for (int j = 0; j < 8; ++j) { h2v[j] = 0; l2v[j] = 0; }
        }
        __syncthreads();
        AhL[t] = h1v; AlL[t] = l1v;
        AhL[o2] = h2v; AlL[o2] = l2v;
        __syncthreads();

        short8 ah[2], al[2], bh[4], bl[4];
#pragma unroll
        for (int st = 0; st < 2; ++st) {
            ah[st] = AhL[(w * 2 + st) * 64 + lane];
            al[st] = AlL[(w * 2 + st) * 64 + lane];
        }
#pragma unroll
        for (int sn = 0; sn < 4; ++sn) {
            bh[sn] = pBh[((size_t)c * NG + g0 + sn) * 64 + lane];
            bl[sn] = pBl[((size_t)c * NG + g0 + sn) * 64 + lane];
        }
#pragma unroll
        for (int st = 0; st < 2; ++st)
#pragma unroll
            for (int sn = 0; sn < 4; ++sn) {
                acc[st][sn] = mfma16(ah[st], bh[sn], acc[st][sn]);
                acc[st][sn] = mfma16(al[st], bh[sn], acc[st][sn]);
                acc[st][sn] = mfma16(ah[st], bl[sn], acc[st][sn]);
            }
    }

    int row0 = bm + w * 32 + (lane >> 4) * 4;
    int col0 = bn + (lane & 15);
#pragma unroll
    for (int st = 0; st < 2; ++st)
#pragma unroll
        for (int r = 0; r < 4; ++r) {
            int row = row0 + st * 16 + r;
            if (row < M) {
#pragma unroll
                for (int sn = 0; sn < 4; ++sn) {
                    int cidx = col0 + sn * 16;
                    float bm_ = b2[cidx] + b2[cidx + 256] + b2[cidx + 512] + b2[cidx + 768];
                    C[(size_t)row * N + cidx] = 0.25f * (acc[st][sn][r] + bm_);
                }
            }
        }
}

// ---------------- attention score parts ----------------

__global__ __launch_bounds__(256) void elr_kernel(const float* __restrict__ z,
                                                  const float* __restrict__ al,
                                                  const float* __restrict__ ar,
                                                  float* __restrict__ el,
                                                  float* __restrict__ er,
                                                  int NH, int F) {
    int gid = blockIdx.x * 256 + threadIdx.x;
    int w = gid >> 6;
    int lane = threadIdx.x & 63;
    if (w >= NH) return;
    int n = w >> 2, h = w & 3;
    const float* zr = z + (size_t)n * (4 * F) + h * F;
    const float* alr = al + h * F;
    const float* arr = ar + h * F;
    float se = 0.f, sr = 0.f;
    for (int f = lane; f < F; f += 64) {
        float zv = zr[f];
        se += zv * alr[f];
        sr += zv * arr[f];
    }
#pragma unroll
    for (int off = 32; off > 0; off >>= 1) {
        se += __shfl_down(se, off);
        sr += __shfl_down(sr, off);
    }
    if (lane == 0) { el[w] = se; er[w] = sr; }
}

// val[h*256+k] = sum_j W2[k,h*256+j]*al2[h,j] ; var likewise with ar2
__global__ __launch_bounds__(256) void proj_av_kernel(const float* __restrict__ W2,
                                                      const float* __restrict__ al2,
                                                      const float* __restrict__ ar2,
                                                      float* __restrict__ val,
                                                      float* __restrict__ var_) {
    int gid = blockIdx.x * 256 + threadIdx.x;
    int w = gid >> 6;
    int lane = threadIdx.x & 63;
    if (w >= 1024) return;
    int h = w >> 8, k = w & 255;
    const float* wrow = W2 + (size_t)k * 1024 + h * 256;
    const float* ap = al2 + h * 256;
    const float* rp = ar2 + h * 256;
    float sv = 0.f, sr = 0.f;
    for (int j = lane; j < 256; j += 64) {
        float x = wrow[j];
        sv += x * ap[j];
        sr += x * rp[j];
    }
#pragma unroll
    for (int off = 32; off > 0; off >>= 1) {
        sv += __shfl_down(sv, off);
        sr += __shfl_down(sr, off);
    }
    if (lane == 0) { val[w] = sv; var_[w] = sr; }
}

// el[n,h] = h1[n,:]·val[h,:], er likewise
__global__ __launch_bounds__(256) void elr2_kernel(const float* __restrict__ h1,
                                                   const float* __restrict__ val,
                                                   const float* __restrict__ var_,
                                                   float* __restrict__ el,
                                                   float* __restrict__ er) {
    int gid = blockIdx.x * 256 + threadIdx.x;
    int w = gid >> 6;
    int lane = threadIdx.x & 63;
    if (w >= NN * 4) return;
    int n = w >> 2, h = w & 3;
    const float* hr = h1 + (size_t)n * 256;
    const float* vp = val + h * 256;
    const float* rp = var_ + h * 256;
    float se = 0.f, sr = 0.f;
    for (int k = lane; k < 256; k += 64) {
        float x = hr[k];
        se += x * vp[k];
        sr += x * rp[k];
    }
#pragma unroll
    for (int off = 32; off > 0; off >>= 1) {
        se += __shfl_down(se, off);
        sr += __shfl_down(sr, off);
    }
    if (lane == 0) { el[w] = se; er[w] = sr; }
}

// ---------------- aggregation, layers 0/1 ----------------

__global__ __launch_bounds__(256) void agg_kernel(const float* __restrict__ z,
                                                  const float* __restrict__ el,
                                                  const float* __restrict__ er,
                                                  const int* __restrict__ offs,
                                                  const int* __restrict__ psrc,
                                                  const float* __restrict__ bias,
                                                  float* __restrict__ out) {
    int n = blockIdx.x;
    int t = threadIdx.x;
    int h = t >> 6;
    __shared__ float p_lds[64][4];
    __shared__ int src_lds[64];
    __shared__ float den_lds[4];
    if (t < 4) den_lds[t] = 0.f;
    int beg = offs[n], end = offs[n + 1];
    float acc = 0.f;
    int e_local = t >> 2, hh = t & 3;
    float er_n = er[n * 4 + hh];
    for (int base = beg; base < end; base += 64) {
        int cnt = min(64, end - base);
        __syncthreads();
        if (e_local < cnt) {
            int s = psrc[base + e_local];
            if (hh == 0) src_lds[e_local] = s;
            float sc = el[s * 4 + hh] + er_n;
            sc = (sc > 0.f) ? sc : 0.2f * sc;
            float p = __expf(sc);
            p_lds[e_local][hh] = p;
            atomicAdd(&den_lds[hh], p);
        }
        __syncthreads();
        for (int e = 0; e < cnt; ++e) {
            acc += p_lds[e][h] * z[(size_t)src_lds[e] * 256 + t];
        }
    }
    __syncthreads();
    float o = acc / fmaxf(den_lds[h], 1e-9f) + bias[t];
    out[(size_t)n * 256 + t] = (o > 0.f) ? o : (__expf(o) - 1.f);
}

// ---------------- layer-2 aggregation of h1: aggH[n, h*256+k] ----------------

__global__ __launch_bounds__(256) void aggH_kernel(const float* __restrict__ h1,
                                                   const float* __restrict__ el,
                                                   const float* __restrict__ er,
                                                   const int* __restrict__ offs,
                                                   const int* __restrict__ psrc,
                                                   float* __restrict__ aggH) {
    int n = blockIdx.x, t = threadIdx.x;
    __shared__ float p_lds[64][4];
    __shared__ int src_lds[64];
    __shared__ float den_lds[4];
    if (t < 4) den_lds[t] = 0.f;
    int beg = offs[n], end = offs[n + 1];
    float a0 = 0.f, a1 = 0.f, a2 = 0.f, a3 = 0.f;
    int e_local = t >> 2, hh = t & 3;
    float er_n = er[n * 4 + hh];
    for (int base = beg; base < end; base += 64) {
        int cnt = min(64, end - base);
        __syncthreads();
        if (e_local < cnt) {
            int s = psrc[base + e_local];
            if (hh == 0) src_lds[e_local] = s;
            float sc = el[s * 4 + hh] + er_n;
            sc = (sc > 0.f) ? sc : 0.2f * sc;
            float p = __expf(sc);
            p_lds[e_local][hh] = p;
            atomicAdd(&den_lds[hh], p);
        }
        __syncthreads();
        for (int e = 0; e < cnt; ++e) {
            float v = h1[(size_t)src_lds[e] * 256 + t];
            a0 += p_lds[e][0] * v;
            a1 += p_lds[e][1] * v;
            a2 += p_lds[e][2] * v;
            a3 += p_lds[e][3] * v;
        }
    }
    __syncthreads();
    float d0 = fmaxf(den_lds[0], 1e-9f);
    float d1 = fmaxf(den_lds[1], 1e-9f);
    float d2 = fmaxf(den_lds[2], 1e-9f);
    float d3 = fmaxf(den_lds[3], 1e-9f);
    float* op = aggH + (size_t)n * 1024;
    op[t] = a0 / d0;
    op[256 + t] = a1 / d1;
    op[512 + t] = a2 / d2;
    op[768 + t] = a3 / d3;
}

// ---------------- launch ----------------

extern "C" void kernel_launch(void* const* d_in, const int* in_sizes, int n_in,
                              void* d_out, int out_size, void* d_ws, size_t ws_size,
                              hipStream_t stream) {
    const float* feat = (const float*)d_in[0];
    const float* W0 = (const float*)d_in[1];
    const float* al0 = (const float*)d_in[2];
    const float* ar0 = (const float*)d_in[3];
    const float* b0 = (const float*)d_in[4];
    const float* W1 = (const float*)d_in[5];
    const float* al1 = (const float*)d_in[6];
    const float* ar1 = (const float*)d_in[7];
    const float* b1 = (const float*)d_in[8];
    const float* W2 = (const float*)d_in[9];
    const float* al2 = (const float*)d_in[10];
    const float* ar2 = (const float*)d_in[11];
    const float* b2 = (const float*)d_in[12];
    const int* src = (const int*)d_in[13];
    const int* dst = (const int*)d_in[14];
    float* out = (float*)d_out;

    // workspace layout (~262.5 MB)
    float* z = (float*)d_ws;                       // 50000*1024 (z0/z1 use first 256 cols; aggH uses all)
    float* hbuf = z + (size_t)NN * 1024;           // 50000*256
    float* el = hbuf + (size_t)NN * 256;           // 200000
    float* er = el + (size_t)NN * NH_HEADS;        // 200000
    int* deg = (int*)(er + (size_t)NN * NH_HEADS); // 50000
    int* offs = deg + NN;                          // 50001 (+1 pad)
    int* cursor = offs + NN + 2;                   // 50000
    int* bsums = cursor + NN;                      // 256
    int* boffs = bsums + 256;                      // 256
    int* psrc = boffs + 256;                       // 800000 (+2 pad)
    short* Bh = (short*)(psrc + NE + 2);           // 262144 shorts
    short* Bl = Bh + 262144;                       // 262144 shorts
    float* val = (float*)(Bl + 262144);            // 1024
    float* var_ = val + 1024;                      // 1024

    // ---- CSR build (by dst) ----
    hipMemsetAsync(deg, 0, NN * sizeof(int), stream);
    hist_kernel<<<(NE + 255) / 256, 256, 0, stream>>>(dst, deg, NE);
    int nb = (NN + 255) / 256;
    scan_block_kernel<<<nb, 256, 0, stream>>>(deg, offs, bsums, NN);
    scan_sums_kernel<<<1, 256, 0, stream>>>(bsums, boffs, nb);
    add_offs_kernel<<<nb, 256, 0, stream>>>(offs, boffs, cursor, NN, NE);
    scatter_kernel<<<(NE + 255) / 256, 256, 0, stream>>>(src, dst, cursor, psrc, NE);

    int mb128 = (NN + 127) / 128; // 391

    // ---- layer 0: 128 -> 4x64, elu ----
    {
        int totB = (128 / 32) * (256 / 16) * 64;
        splitB_kernel<<<(totB + 255) / 256, 256, 0, stream>>>(W0, Bh, Bl, 128, 256);
        gemm_mfma<<<dim3(4, mb128), 256, 0, stream>>>(feat, Bh, Bl, z, NN, 256, 128);
    }
    elr_kernel<<<(NN * NH_HEADS) / 4, 256, 0, stream>>>(z, al0, ar0, el, er, NN * NH_HEADS, 64);
    agg_kernel<<<NN, 256, 0, stream>>>(z, el, er, offs, psrc, b0, hbuf);

    // ---- layer 1: 256 -> 4x64, elu ----
    {
        int totB = (256 / 32) * (256 / 16) * 64;
        splitB_kernel<<<(totB + 255) / 256, 256, 0, stream>>>(W1, Bh, Bl, 256, 256);
        gemm_mfma<<<dim3(4, mb128), 256, 0, stream>>>(hbuf, Bh, Bl, z, NN, 256, 256);
    }
    elr_kernel<<<(NN * NH_HEADS) / 4, 256, 0, stream>>>(z, al1, ar1, el, er, NN * NH_HEADS, 64);
    agg_kernel<<<NN, 256, 0, stream>>>(z, el, er, offs, psrc, b1, hbuf);

    // ---- layer 2 (restructured): aggregate h1, then project ----
    proj_av_kernel<<<256, 256, 0, stream>>>(W2, al2, ar2, val, var_);
    elr2_kernel<<<NN, 256, 0, stream>>>(hbuf, val, var_, el, er);
    aggH_kernel<<<NN, 256, 0, stream>>>(hbuf, el, er, offs, psrc, z);
    splitB2_kernel<<<(32768 + 255) / 256, 256, 0, stream>>>(W2, Bh, Bl);
    gemm_fin<<<dim3(4, mb128), 256, 0, stream>>>(z, Bh, Bl, b2, out, NN, 256, 1024);
}

// Round 5
// 888.833 us; speedup vs baseline: 1.9539x; 1.1196x over previous
//
#include <hip/hip_runtime.h>
#include <hip/hip_bf16.h>

// GAT: 3 layers. N=50000 nodes, E=800000 edges, H=4 heads.
// R5: all GEMMs have N=256 -> one block spans full N (BM=64, 4 waves split
// by columns). A read from HBM exactly once (was 4x). bf16 hi/lo split MFMA.

#define NN 50000
#define NE 800000
#define NH_HEADS 4

typedef __attribute__((ext_vector_type(8))) short short8;
typedef __attribute__((ext_vector_type(4))) float floatx4;

__device__ inline short f2bf_rne(float x) {
    union { float f; unsigned u; } v; v.f = x;
    unsigned r = v.u + 0x7fff + ((v.u >> 16) & 1);
    return (short)(r >> 16);
}
__device__ inline float bf2f(short s) {
    union { unsigned u; float f; } v; v.u = ((unsigned)(unsigned short)s) << 16;
    return v.f;
}

__device__ inline void cvt8(const float* __restrict__ p, short8& h, short8& l) {
    float4 x0 = ((const float4*)p)[0];
    float4 x1 = ((const float4*)p)[1];
    float xs[8] = {x0.x, x0.y, x0.z, x0.w, x1.x, x1.y, x1.z, x1.w};
#pragma unroll
    for (int j = 0; j < 8; ++j) {
        union { float f; unsigned u; } v; v.f = xs[j];
        short hh = (short)(v.u >> 16);
        h[j] = hh;
        float r = v.f - bf2f(hh);
        union { float f; unsigned u; } rv; rv.f = r;
        l[j] = (short)(rv.u >> 16);
    }
}

// ---------------- CSR build ----------------

__global__ void hist_kernel(const int* __restrict__ dst, int* __restrict__ deg, int E) {
    int e = blockIdx.x * 256 + threadIdx.x;
    if (e < E) atomicAdd(&deg[dst[e]], 1);
}

__global__ void scan_block_kernel(const int* __restrict__ deg, int* __restrict__ offs,
                                  int* __restrict__ bsums, int n) {
    __shared__ int s[256];
    int tid = threadIdx.x;
    int i = blockIdx.x * 256 + tid;
    int v = (i < n) ? deg[i] : 0;
    s[tid] = v;
    __syncthreads();
    for (int off = 1; off < 256; off <<= 1) {
        int x = (tid >= off) ? s[tid - off] : 0;
        __syncthreads();
        s[tid] += x;
        __syncthreads();
    }
    if (i < n) offs[i] = s[tid] - v;
    if (tid == 255) bsums[blockIdx.x] = s[255];
}

__global__ void scan_sums_kernel(const int* __restrict__ bsums, int* __restrict__ boffs, int nb) {
    __shared__ int s[256];
    int tid = threadIdx.x;
    int v = (tid < nb) ? bsums[tid] : 0;
    s[tid] = v;
    __syncthreads();
    for (int off = 1; off < 256; off <<= 1) {
        int x = (tid >= off) ? s[tid - off] : 0;
        __syncthreads();
        s[tid] += x;
        __syncthreads();
    }
    boffs[tid] = s[tid] - v;
}

__global__ void add_offs_kernel(int* __restrict__ offs, const int* __restrict__ boffs,
                                int* __restrict__ cursor, int n, int total) {
    int i = blockIdx.x * 256 + threadIdx.x;
    if (i < n) {
        int o = offs[i] + boffs[blockIdx.x];
        offs[i] = o;
        cursor[i] = o;
    }
    if (i == 0) offs[n] = total;
}

__global__ void scatter_kernel(const int* __restrict__ src, const int* __restrict__ dst,
                               int* __restrict__ cursor, int* __restrict__ psrc, int E) {
    int e = blockIdx.x * 256 + threadIdx.x;
    if (e < E) {
        int p = atomicAdd(&cursor[dst[e]], 1);
        psrc[p] = src[e];
    }
}

// ---------------- B -> bf16 hi/lo in MFMA B-fragment order ----------------
// layout: offset (short8) = (c*(N/16)+g)*64 + lane ; lane=(n&15)+16*((k&31)>>3), j=k&7

__global__ __launch_bounds__(256) void splitB_kernel(const float* __restrict__ B,
                                                     short* __restrict__ hi,
                                                     short* __restrict__ lo,
                                                     int K, int N) {
    int tid = blockIdx.x * 256 + threadIdx.x;
    int NG = N >> 4;
    int total = (K >> 5) * NG * 64;
    if (tid >= total) return;
    int lane = tid & 63;
    int rc = tid >> 6;
    int g = rc % NG, c = rc / NG;
    int n = g * 16 + (lane & 15);
    int k = c * 32 + (lane >> 4) * 8;
    short8 hv, lv;
#pragma unroll
    for (int j = 0; j < 8; ++j) {
        float x = B[(size_t)(k + j) * N + n];
        short h = f2bf_rne(x);
        hv[j] = h;
        lv[j] = f2bf_rne(x - bf2f(h));
    }
    ((short8*)hi)[tid] = hv;
    ((short8*)lo)[tid] = lv;
}

// permuted-W2: Bp[h*256+k, c] = W2[k, h*256+c]; K=1024, N=256
__global__ __launch_bounds__(256) void splitB2_kernel(const float* __restrict__ W2,
                                                      short* __restrict__ hi,
                                                      short* __restrict__ lo) {
    int tid = blockIdx.x * 256 + threadIdx.x;
    const int NG = 16;
    int total = (1024 >> 5) * NG * 64;   // 32768
    if (tid >= total) return;
    int lane = tid & 63;
    int rc = tid >> 6;
    int g = rc % NG, c = rc / NG;
    int n = g * 16 + (lane & 15);
    int kk = c * 32 + (lane >> 4) * 8;
    short8 hv, lv;
#pragma unroll
    for (int j = 0; j < 8; ++j) {
        int kg = kk + j;
        int h = kg >> 8, k = kg & 255;
        float x = W2[(size_t)k * 1024 + h * 256 + n];
        short hb = f2bf_rne(x);
        hv[j] = hb;
        lv[j] = f2bf_rne(x - bf2f(hb));
    }
    ((short8*)hi)[tid] = hv;
    ((short8*)lo)[tid] = lv;
}

// ---------------- MFMA GEMM, N=256 fixed, A read once ----------------
// block: 64 rows x 256 cols; wave w owns rows [bm,bm+64) x cols [w*64,(w+1)*64).
// A staged fp32->hi/lo in LDS once per block per chunk.
// epilogue: bias4 == nullptr -> C=acc ; else C = 0.25*(acc + sum_h bias4[h*256+c]).

__device__ inline floatx4 mfma16(short8 a, short8 b, floatx4 c) {
    return __builtin_amdgcn_mfma_f32_16x16x32_bf16(a, b, c, 0, 0, 0);
}

__global__ __launch_bounds__(256) void gemm_n256(const float* __restrict__ A,
                                                 const short* __restrict__ Bh,
                                                 const short* __restrict__ Bl,
                                                 const float* __restrict__ bias4,
                                                 float* __restrict__ C,
                                                 int M, int K) {
    int KC = K >> 5;
    __shared__ short8 AhL[256];   // 4 m-tiles x 64 lanes
    __shared__ short8 AlL[256];
    int t = threadIdx.x;
    int lane = t & 63;
    int w = t >> 6;
    int bm = blockIdx.x * 64;
    const short8* pBh = (const short8*)Bh;
    const short8* pBl = (const short8*)Bl;

    floatx4 acc[4][4] = {};

    // staging: thread t -> octet t of the 64x32 tile
    int ms = ((t >> 6) << 4) + (t & 15);
    int kos = (t >> 4) & 3;
    bool vs = (bm + ms) < M;
    const float* As = A + (size_t)(bm + ms) * K + kos * 8;
    int g0 = w * 4;

    for (int c = 0; c < KC; ++c) {
        short8 hv, lv;
        if (vs) cvt8(As + c * 32, hv, lv);
        else {
#pragma unroll
            for (int j = 0; j < 8; ++j) { hv[j] = 0; lv[j] = 0; }
        }
        __syncthreads();
        AhL[t] = hv; AlL[t] = lv;
        __syncthreads();

        short8 bh[4], bl[4];
#pragma unroll
        for (int g = 0; g < 4; ++g) {
            bh[g] = pBh[((size_t)c * 16 + g0 + g) * 64 + lane];
            bl[g] = pBl[((size_t)c * 16 + g0 + g) * 64 + lane];
        }
#pragma unroll
        for (int mt = 0; mt < 4; ++mt) {
            short8 ah = AhL[mt * 64 + lane];
            short8 al = AlL[mt * 64 + lane];
#pragma unroll
            for (int g = 0; g < 4; ++g) {
                acc[mt][g] = mfma16(ah, bh[g], acc[mt][g]);
                acc[mt][g] = mfma16(al, bh[g], acc[mt][g]);
                acc[mt][g] = mfma16(ah, bl[g], acc[mt][g]);
            }
        }
    }

    // C/D layout: col = lane&15, row = (lane>>4)*4 + reg
    int rowb = bm + (lane >> 4) * 4;
    int colb = w * 64 + (lane & 15);
#pragma unroll
    for (int mt = 0; mt < 4; ++mt) {
#pragma unroll
        for (int r = 0; r < 4; ++r) {
            int row = rowb + mt * 16 + r;
            if (row < M) {
#pragma unroll
                for (int g = 0; g < 4; ++g) {
                    int col = colb + g * 16;
                    float v = acc[mt][g][r];
                    if (bias4) {
                        v = 0.25f * (v + bias4[col] + bias4[col + 256] +
                                     bias4[col + 512] + bias4[col + 768]);
                    }
                    C[(size_t)row * 256 + col] = v;
                }
            }
        }
    }
}

// ---------------- attention score parts ----------------

__global__ __launch_bounds__(256) void elr_kernel(const float* __restrict__ z,
                                                  const float* __restrict__ al,
                                                  const float* __restrict__ ar,
                                                  float* __restrict__ el,
                                                  float* __restrict__ er,
                                                  int NH, int F) {
    int gid = blockIdx.x * 256 + threadIdx.x;
    int w = gid >> 6;
    int lane = threadIdx.x & 63;
    if (w >= NH) return;
    int n = w >> 2, h = w & 3;
    const float* zr = z + (size_t)n * (4 * F) + h * F;
    const float* alr = al + h * F;
    const float* arr = ar + h * F;
    float se = 0.f, sr = 0.f;
    for (int f = lane; f < F; f += 64) {
        float zv = zr[f];
        se += zv * alr[f];
        sr += zv * arr[f];
    }
#pragma unroll
    for (int off = 32; off > 0; off >>= 1) {
        se += __shfl_down(se, off);
        sr += __shfl_down(sr, off);
    }
    if (lane == 0) { el[w] = se; er[w] = sr; }
}

// val[h*256+k] = sum_j W2[k,h*256+j]*al2[h,j] ; var likewise with ar2
__global__ __launch_bounds__(256) void proj_av_kernel(const float* __restrict__ W2,
                                                      const float* __restrict__ al2,
                                                      const float* __restrict__ ar2,
                                                      float* __restrict__ val,
                                                      float* __restrict__ var_) {
    int gid = blockIdx.x * 256 + threadIdx.x;
    int w = gid >> 6;
    int lane = threadIdx.x & 63;
    if (w >= 1024) return;
    int h = w >> 8, k = w & 255;
    const float* wrow = W2 + (size_t)k * 1024 + h * 256;
    const float* ap = al2 + h * 256;
    const float* rp = ar2 + h * 256;
    float sv = 0.f, sr = 0.f;
    for (int j = lane; j < 256; j += 64) {
        float x = wrow[j];
        sv += x * ap[j];
        sr += x * rp[j];
    }
#pragma unroll
    for (int off = 32; off > 0; off >>= 1) {
        sv += __shfl_down(sv, off);
        sr += __shfl_down(sr, off);
    }
    if (lane == 0) { val[w] = sv; var_[w] = sr; }
}

// el[n,h] = h1[n,:]·val[h,:], er likewise
__global__ __launch_bounds__(256) void elr2_kernel(const float* __restrict__ h1,
                                                   const float* __restrict__ val,
                                                   const float* __restrict__ var_,
                                                   float* __restrict__ el,
                                                   float* __restrict__ er) {
    int gid = blockIdx.x * 256 + threadIdx.x;
    int w = gid >> 6;
    int lane = threadIdx.x & 63;
    if (w >= NN * 4) return;
    int n = w >> 2, h = w & 3;
    const float* hr = h1 + (size_t)n * 256;
    const float* vp = val + h * 256;
    const float* rp = var_ + h * 256;
    float se = 0.f, sr = 0.f;
    for (int k = lane; k < 256; k += 64) {
        float x = hr[k];
        se += x * vp[k];
        sr += x * rp[k];
    }
#pragma unroll
    for (int off = 32; off > 0; off >>= 1) {
        se += __shfl_down(se, off);
        sr += __shfl_down(sr, off);
    }
    if (lane == 0) { el[w] = se; er[w] = sr; }
}

// ---------------- aggregation, layers 0/1 ----------------

__global__ __launch_bounds__(256) void agg_kernel(const float* __restrict__ z,
                                                  const float* __restrict__ el,
                                                  const float* __restrict__ er,
                                                  const int* __restrict__ offs,
                                                  const int* __restrict__ psrc,
                                                  const float* __restrict__ bias,
                                                  float* __restrict__ out) {
    int n = blockIdx.x;
    int t = threadIdx.x;
    int h = t >> 6;
    __shared__ float p_lds[64][4];
    __shared__ int src_lds[64];
    __shared__ float den_lds[4];
    if (t < 4) den_lds[t] = 0.f;
    int beg = offs[n], end = offs[n + 1];
    float acc = 0.f;
    int e_local = t >> 2, hh = t & 3;
    float er_n = er[n * 4 + hh];
    for (int base = beg; base < end; base += 64) {
        int cnt = min(64, end - base);
        __syncthreads();
        if (e_local < cnt) {
            int s = psrc[base + e_local];
            if (hh == 0) src_lds[e_local] = s;
            float sc = el[s * 4 + hh] + er_n;
            sc = (sc > 0.f) ? sc : 0.2f * sc;
            float p = __expf(sc);
            p_lds[e_local][hh] = p;
            atomicAdd(&den_lds[hh], p);
        }
        __syncthreads();
        for (int e = 0; e < cnt; ++e) {
            acc += p_lds[e][h] * z[(size_t)src_lds[e] * 256 + t];
        }
    }
    __syncthreads();
    float o = acc / fmaxf(den_lds[h], 1e-9f) + bias[t];
    out[(size_t)n * 256 + t] = (o > 0.f) ? o : (__expf(o) - 1.f);
}

// ---------------- layer-2 aggregation of h1: aggH[n, h*256+k] ----------------

__global__ __launch_bounds__(256) void aggH_kernel(const float* __restrict__ h1,
                                                   const float* __restrict__ el,
                                                   const float* __restrict__ er,
                                                   const int* __restrict__ offs,
                                                   const int* __restrict__ psrc,
                                                   float* __restrict__ aggH) {
    int n = blockIdx.x, t = threadIdx.x;
    __shared__ float p_lds[64][4];
    __shared__ int src_lds[64];
    __shared__ float den_lds[4];
    if (t < 4) den_lds[t] = 0.f;
    int beg = offs[n], end = offs[n + 1];
    float a0 = 0.f, a1 = 0.f, a2 = 0.f, a3 = 0.f;
    int e_local = t >> 2, hh = t & 3;
    float er_n = er[n * 4 + hh];
    for (int base = beg; base < end; base += 64) {
        int cnt = min(64, end - base);
        __syncthreads();
        if (e_local < cnt) {
            int s = psrc[base + e_local];
            if (hh == 0) src_lds[e_local] = s;
            float sc = el[s * 4 + hh] + er_n;
            sc = (sc > 0.f) ? sc : 0.2f * sc;
            float p = __expf(sc);
            p_lds[e_local][hh] = p;
            atomicAdd(&den_lds[hh], p);
        }
        __syncthreads();
        for (int e = 0; e < cnt; ++e) {
            float v = h1[(size_t)src_lds[e] * 256 + t];
            a0 += p_lds[e][0] * v;
            a1 += p_lds[e][1] * v;
            a2 += p_lds[e][2] * v;
            a3 += p_lds[e][3] * v;
        }
    }
    __syncthreads();
    float d0 = fmaxf(den_lds[0], 1e-9f);
    float d1 = fmaxf(den_lds[1], 1e-9f);
    float d2 = fmaxf(den_lds[2], 1e-9f);
    float d3 = fmaxf(den_lds[3], 1e-9f);
    float* op = aggH + (size_t)n * 1024;
    op[t] = a0 / d0;
    op[256 + t] = a1 / d1;
    op[512 + t] = a2 / d2;
    op[768 + t] = a3 / d3;
}

// ---------------- launch ----------------

extern "C" void kernel_launch(void* const* d_in, const int* in_sizes, int n_in,
                              void* d_out, int out_size, void* d_ws, size_t ws_size,
                              hipStream_t stream) {
    const float* feat = (const float*)d_in[0];
    const float* W0 = (const float*)d_in[1];
    const float* al0 = (const float*)d_in[2];
    const float* ar0 = (const float*)d_in[3];
    const float* b0 = (const float*)d_in[4];
    const float* W1 = (const float*)d_in[5];
    const float* al1 = (const float*)d_in[6];
    const float* ar1 = (const float*)d_in[7];
    const float* b1 = (const float*)d_in[8];
    const float* W2 = (const float*)d_in[9];
    const float* al2 = (const float*)d_in[10];
    const float* ar2 = (const float*)d_in[11];
    const float* b2 = (const float*)d_in[12];
    const int* src = (const int*)d_in[13];
    const int* dst = (const int*)d_in[14];
    float* out = (float*)d_out;

    // workspace layout (~262.5 MB)
    float* z = (float*)d_ws;                       // 50000*1024
    float* hbuf = z + (size_t)NN * 1024;           // 50000*256
    float* el = hbuf + (size_t)NN * 256;           // 200000
    float* er = el + (size_t)NN * NH_HEADS;        // 200000
    int* deg = (int*)(er + (size_t)NN * NH_HEADS); // 50000
    int* offs = deg + NN;                          // 50001 (+1 pad)
    int* cursor = offs + NN + 2;                   // 50000
    int* bsums = cursor + NN;                      // 256
    int* boffs = bsums + 256;                      // 256
    int* psrc = boffs + 256;                       // 800000 (+2 pad)
    short* Bh = (short*)(psrc + NE + 2);           // 262144 shorts
    short* Bl = Bh + 262144;                       // 262144 shorts
    float* val = (float*)(Bl + 262144);            // 1024
    float* var_ = val + 1024;                      // 1024

    // ---- CSR build (by dst) ----
    hipMemsetAsync(deg, 0, NN * sizeof(int), stream);
    hist_kernel<<<(NE + 255) / 256, 256, 0, stream>>>(dst, deg, NE);
    int nb = (NN + 255) / 256;
    scan_block_kernel<<<nb, 256, 0, stream>>>(deg, offs, bsums, NN);
    scan_sums_kernel<<<1, 256, 0, stream>>>(bsums, boffs, nb);
    add_offs_kernel<<<nb, 256, 0, stream>>>(offs, boffs, cursor, NN, NE);
    scatter_kernel<<<(NE + 255) / 256, 256, 0, stream>>>(src, dst, cursor, psrc, NE);

    int mb64 = (NN + 63) / 64; // 782

    // ---- layer 0: 128 -> 4x64, elu ----
    {
        int totB = (128 / 32) * (256 / 16) * 64;
        splitB_kernel<<<(totB + 255) / 256, 256, 0, stream>>>(W0, Bh, Bl, 128, 256);
        gemm_n256<<<mb64, 256, 0, stream>>>(feat, Bh, Bl, nullptr, z, NN, 128);
    }
    elr_kernel<<<(NN * NH_HEADS) / 4, 256, 0, stream>>>(z, al0, ar0, el, er, NN * NH_HEADS, 64);
    agg_kernel<<<NN, 256, 0, stream>>>(z, el, er, offs, psrc, b0, hbuf);

    // ---- layer 1: 256 -> 4x64, elu ----
    {
        int totB = (256 / 32) * (256 / 16) * 64;
        splitB_kernel<<<(totB + 255) / 256, 256, 0, stream>>>(W1, Bh, Bl, 256, 256);
        gemm_n256<<<mb64, 256, 0, stream>>>(hbuf, Bh, Bl, nullptr, z, NN, 256);
    }
    elr_kernel<<<(NN * NH_HEADS) / 4, 256, 0, stream>>>(z, al1, ar1, el, er, NN * NH_HEADS, 64);
    agg_kernel<<<NN, 256, 0, stream>>>(z, el, er, offs, psrc, b1, hbuf);

    // ---- layer 2 (restructured): aggregate h1, then project ----
    proj_av_kernel<<<256, 256, 0, stream>>>(W2, al2, ar2, val, var_);
    elr2_kernel<<<NN, 256, 0, stream>>>(hbuf, val, var_, el, er);
    aggH_kernel<<<NN, 256, 0, stream>>>(hbuf, el, er, offs, psrc, z);
    splitB2_kernel<<<(32768 + 255) / 256, 256, 0, stream>>>(W2, Bh, Bl);
    gemm_n256<<<mb64, 256, 0, stream>>>(z, Bh, Bl, b2, out, NN, 1024);
}